// Round 5
// baseline (290.849 us; speedup 1.0000x reference)
//
#include <hip/hip_runtime.h>

#define N_NODES 50000
#define N_EDGES 800000
#define CH      128
#define NBUK    196          // buckets of 256 nodes: dst>>8, max 49999>>8 = 195
#define B_A     128          // phase-A blocks
#define EPB     6250         // edges per phase-A block (128*6250 = 800000)
#define CAP     5120         // LDS capacity per bucket in phase B (mean 4096)

typedef unsigned short u16;
typedef unsigned int   u32;
typedef __bf16 bf16x8 __attribute__((ext_vector_type(8)));
typedef float  f32x4  __attribute__((ext_vector_type(4)));

__device__ __forceinline__ float bf_lo(u32 v){ return __uint_as_float(v << 16); }
__device__ __forceinline__ float bf_hi(u32 v){ return __uint_as_float(v & 0xffff0000u); }
__device__ __forceinline__ u32 bf_pack(float a, float b){
    u32 ua = __float_as_uint(a), ub = __float_as_uint(b);
    ua += 0x7fffu + ((ua >> 16) & 1u);
    ub += 0x7fffu + ((ub >> 16) & 1u);
    return (ua >> 16) | (ub & 0xffff0000u);
}
__device__ __forceinline__ u16 f2bf(float a){
    u32 ua = __float_as_uint(a);
    ua += 0x7fffu + ((ua >> 16) & 1u);
    return (u16)(ua >> 16);
}
__device__ __forceinline__ void addu4(uint4 v, float* a){
    a[0] += bf_lo(v.x); a[1] += bf_hi(v.x);
    a[2] += bf_lo(v.y); a[3] += bf_hi(v.y);
    a[4] += bf_lo(v.z); a[5] += bf_hi(v.z);
    a[6] += bf_lo(v.w); a[7] += bf_hi(v.w);
}

// inclusive block-scan of one int per thread (256 threads, 4 waves)
__device__ __forceinline__ int blockScan256(int v, int* ws, int t) {
    int lane = t & 63, w = t >> 6;
    #pragma unroll
    for (int off = 1; off < 64; off <<= 1) {
        int u = __shfl_up(v, off);
        if (lane >= off) v += u;
    }
    if (lane == 63) ws[w] = v;
    __syncthreads();
    int add = 0;
    for (int k = 0; k < w; k++) add += ws[k];
    return v + add;
}

// ---- prep: transpose W1a/W1b/W2a (fp32 [in][out]) -> bf16 [out][in];
//      fold Wc = W2b@Wfc (fp32), bc = b2b@Wfc + bfc (fp32)
__global__ void prep_kernel(const float* __restrict__ W1a, const float* __restrict__ W1b,
                            const float* __restrict__ W2a, const float* __restrict__ W2b,
                            const float* __restrict__ Wfc, const float* __restrict__ b2b,
                            const float* __restrict__ bfc,
                            u16* __restrict__ wt1a, u16* __restrict__ wt1b,
                            u16* __restrict__ wt2a,
                            float* __restrict__ Wc, float* __restrict__ bc) {
    int b = blockIdx.x, t = threadIdx.x;
    if (b < 192) {
        int g  = b * 256 + t;
        int mi = g >> 14;
        int p  = g & 16383;
        int k  = p >> 7, m = p & 127;
        const float* src = (mi == 0) ? W1a : (mi == 1) ? W1b : W2a;
        u16* dst         = (mi == 0) ? wt1a : (mi == 1) ? wt1b : wt2a;
        dst[m * 128 + k] = f2bf(src[k * 128 + m]);
    } else {
        int j = t >> 1, o = t & 1;
        float s = 0.f;
        for (int k = 0; k < 128; k++)
            s += W2b[j * 128 + k] * Wfc[k * 2 + o];
        Wc[j * 2 + o] = s;
        if (t < 2) {
            float s2 = 0.f;
            for (int k = 0; k < 128; k++)
                s2 += b2b[k] * Wfc[k * 2 + t];
            bc[t] = s2 + bfc[t];
        }
    }
}

// ---- CSR phase A: per-block bucket sort (dst>>8) staged in LDS, linear flush.
//      + grid-stride fp32->bf16 conversion of x appended (independent work).
__launch_bounds__(256)
__global__ void binA_kernel(const int* __restrict__ esrc, const int* __restrict__ edst,
                            u32* __restrict__ binned, int* __restrict__ startTab,
                            int* __restrict__ cntTab,
                            const float* __restrict__ xsrc, u32* __restrict__ xb) {
    __shared__ int hist[NBUK];
    __shared__ int cur[NBUK];
    __shared__ u32 ebuf[EPB];
    __shared__ int ws[4];
    int t = threadIdx.x, blk = blockIdx.x;
    int base = blk * EPB;
    for (int i = t; i < NBUK; i += 256) hist[i] = 0;
    __syncthreads();
    for (int i = t; i < EPB; i += 256)
        atomicAdd(&hist[edst[base + i] >> 8], 1);
    __syncthreads();
    int v = (t < NBUK) ? hist[t] : 0;
    int incl = blockScan256(v, ws, t);
    int excl = incl - v;
    if (t < NBUK) {
        startTab[blk * NBUK + t] = excl;
        cntTab[blk * NBUK + t]   = v;
        cur[t] = excl;
    }
    __syncthreads();
    for (int i = t; i < EPB; i += 256) {
        int d = edst[base + i], s = esrc[base + i];
        int p = atomicAdd(&cur[d >> 8], 1);
        ebuf[p] = (u32)s | ((u32)(d & 255) << 16);   // src(16b) | dst_local(8b)
    }
    __syncthreads();
    for (int i = t; i < EPB; i += 256)               // linear flush: full lines
        binned[base + i] = ebuf[i];
    // fp32 x -> packed bf16 (grid-stride, independent of binning)
    const int total = N_NODES * 64;
    for (int i = blk * 256 + t; i < total; i += B_A * 256) {
        float2 f = ((const float2*)xsrc)[i];
        xb[i] = bf_pack(f.x, f.y);
    }
}

// bucket totals + exclusive scan (tiny)
__global__ void bscan_kernel(const int* __restrict__ cntTab, int* __restrict__ bucketBase,
                             int* __restrict__ offs) {
    __shared__ int ws[4];
    int t = threadIdx.x;
    int s = 0;
    if (t < NBUK) {
        #pragma unroll 8
        for (int blk = 0; blk < B_A; blk++) s += cntTab[blk * NBUK + t];
    }
    int incl = blockScan256(s, ws, t);
    if (t < NBUK) bucketBase[t] = incl - s;
    if (t == 0) offs[N_NODES] = N_EDGES;
}

// ---- CSR phase B: one block per bucket; gather runs, local sort in LDS,
//      linear flush to csr; write offs.
__launch_bounds__(256)
__global__ void binB_kernel(const u32* __restrict__ binned, const int* __restrict__ startTab,
                            const int* __restrict__ cntTab, const int* __restrict__ bucketBase,
                            int* __restrict__ offs, int* __restrict__ csr) {
    __shared__ u32 ebuf[CAP];
    __shared__ int cbuf[CAP];
    __shared__ int runoff[B_A + 1];
    __shared__ int runstart[B_A];
    __shared__ int hist[256];
    __shared__ int cursor[256];
    __shared__ int ws[4];
    int b = blockIdx.x, t = threadIdx.x;
    int c = (t < B_A) ? cntTab[t * NBUK + b] : 0;
    int incl = blockScan256(c, ws, t);
    if (t < B_A) {
        runoff[t]   = incl - c;
        runstart[t] = t * EPB + startTab[t * NBUK + b];
    }
    if (t == B_A - 1) runoff[B_A] = incl;
    hist[t] = 0;
    __syncthreads();
    int tot = runoff[B_A];
    if (tot > CAP) tot = CAP;
    for (int i = t; i < tot; i += 256) { // flat gather: binary search run
        int lo = 0, hi = B_A;
        while (hi - lo > 1) {
            int mid = (lo + hi) >> 1;
            if (runoff[mid] <= i) lo = mid; else hi = mid;
        }
        ebuf[i] = binned[runstart[lo] + (i - runoff[lo])];
    }
    __syncthreads();
    for (int i = t; i < tot; i += 256)
        atomicAdd(&hist[ebuf[i] >> 16], 1);
    __syncthreads();
    int hv = hist[t];
    int hincl = blockScan256(hv, ws, t);
    int hexcl = hincl - hv;
    cursor[t] = hexcl;
    int node = (b << 8) + t;
    if (node < N_NODES) offs[node] = bucketBase[b] + hexcl;
    __syncthreads();
    for (int i = t; i < tot; i += 256) {
        u32 e = ebuf[i];
        int p = atomicAdd(&cursor[e >> 16], 1);
        cbuf[p] = (int)(e & 0xFFFFu);
    }
    __syncthreads();
    int gb = bucketBase[b];
    for (int i = t; i < tot; i += 256)
        csr[gb + i] = cbuf[i];
}

// ---- fused agg + GEMM ------------------------------------------------------
// A-tile (64 rows) is produced in-kernel: per node, 16 lanes x uint4 gather of
// neighbor rows, fp32 accumulate, pack -> LDS; then MFMA vs W (128x128).
// MODE 0: C = relu(A@W + bias) -> bf16 global.
// MODE 1: out = relu(A@W + bias) @ Wc + bc -> fp32 [n,2]  (FC folded, no C write)
template<int MODE>
__launch_bounds__(256)
__global__ void fused_agg_gemm(const u32* __restrict__ xb, const u16* __restrict__ Wt,
                               const float* __restrict__ bias,
                               const int* __restrict__ offs, const int* __restrict__ csr,
                               u16* __restrict__ C,
                               const float* __restrict__ Wc, const float* __restrict__ bc,
                               float2* __restrict__ out, int n) {
    __shared__ u16 Ws[128][136];
    __shared__ u16 As[64][136];
    int t = threadIdx.x;
    {   // stage W
        int r = t >> 1, p = t & 1;
        const uint4* s = (const uint4*)(Wt + r * 128 + p * 64);
        uint4* d = (uint4*)&Ws[r][p * 64];
        #pragma unroll
        for (int i = 0; i < 8; i++) d[i] = s[i];
    }
    int row0 = blockIdx.x * 64;
    int w = t >> 6, lane = t & 63;
    int g4 = lane >> 4, l16 = lane & 15;
    const uint4* xp = (const uint4*)xb;       // row = 16 x uint4 (128 bf16)
    #pragma unroll
    for (int p = 0; p < 4; p++) {             // 4 nodes/wave/pass, 4 passes
        int rl = w * 16 + p * 4 + g4;
        int node = row0 + rl;
        float a[8] = {0.f,0.f,0.f,0.f,0.f,0.f,0.f,0.f};
        if (node < n) {
            addu4(xp[(size_t)node * 16 + l16], a);   // self term
            int j = offs[node], jend = offs[node + 1];
            for (; j + 4 <= jend; j += 4) {
                int s0 = csr[j], s1 = csr[j + 1], s2 = csr[j + 2], s3 = csr[j + 3];
                uint4 w0 = xp[(size_t)s0 * 16 + l16];
                uint4 w1 = xp[(size_t)s1 * 16 + l16];
                uint4 w2 = xp[(size_t)s2 * 16 + l16];
                uint4 w3 = xp[(size_t)s3 * 16 + l16];
                addu4(w0, a); addu4(w1, a); addu4(w2, a); addu4(w3, a);
            }
            for (; j < jend; j++)
                addu4(xp[(size_t)csr[j] * 16 + l16], a);
        }
        uint4 pk = make_uint4(bf_pack(a[0], a[1]), bf_pack(a[2], a[3]),
                              bf_pack(a[4], a[5]), bf_pack(a[6], a[7]));
        *(uint4*)&As[rl][l16 * 8] = pk;
    }
    __syncthreads();

    int lm = lane & 15, lq = lane >> 4;
    f32x4 acc[8];
    #pragma unroll
    for (int c = 0; c < 8; c++) acc[c] = (f32x4){0.f, 0.f, 0.f, 0.f};
    #pragma unroll
    for (int kk = 0; kk < 4; kk++) {
        bf16x8 af = *(const bf16x8*)&As[w * 16 + lm][kk * 32 + lq * 8];
        #pragma unroll
        for (int c = 0; c < 8; c++) {
            bf16x8 bf = *(const bf16x8*)&Ws[c * 16 + lm][kk * 32 + lq * 8];
            acc[c] = __builtin_amdgcn_mfma_f32_16x16x32_bf16(af, bf, acc[c], 0, 0, 0);
        }
    }
    if (MODE == 0) {
        #pragma unroll
        for (int c = 0; c < 8; c++) {
            #pragma unroll
            for (int r = 0; r < 4; r++) {
                int row = row0 + w * 16 + lq * 4 + r;
                int col = c * 16 + lm;
                if (row < n) {
                    float v = acc[c][r] + bias[col];
                    v = v > 0.f ? v : 0.f;
                    C[(size_t)row * 128 + col] = f2bf(v);
                }
            }
        }
    } else {
        float p0[4] = {0,0,0,0}, p1[4] = {0,0,0,0};
        #pragma unroll
        for (int c = 0; c < 8; c++) {
            int col = c * 16 + lm;
            float bcol = bias[col];
            float2 wc = ((const float2*)Wc)[col];
            #pragma unroll
            for (int r = 0; r < 4; r++) {
                float v = acc[c][r] + bcol;
                v = v > 0.f ? v : 0.f;
                p0[r] += v * wc.x;
                p1[r] += v * wc.y;
            }
        }
        #pragma unroll
        for (int off = 1; off < 16; off <<= 1) {
            #pragma unroll
            for (int r = 0; r < 4; r++) {
                p0[r] += __shfl_xor(p0[r], off);
                p1[r] += __shfl_xor(p1[r], off);
            }
        }
        if (lm == 0) {
            float b0 = bc[0], b1 = bc[1];
            #pragma unroll
            for (int r = 0; r < 4; r++) {
                int row = row0 + w * 16 + lq * 4 + r;
                if (row < n) out[row] = make_float2(p0[r] + b0, p1[r] + b1);
            }
        }
    }
}

// ---- plain GEMM (conv1 second linear + outer relu) -------------------------
__launch_bounds__(256)
__global__ void gemm_relu_kernel(const u16* __restrict__ A, const u16* __restrict__ Wt,
                                 const float* __restrict__ bias, u16* __restrict__ C,
                                 int n) {
    __shared__ u16 Ws[128][136];
    __shared__ u16 As[64][136];
    int t = threadIdx.x;
    {
        int r = t >> 1, p = t & 1;
        const uint4* s = (const uint4*)(Wt + r * 128 + p * 64);
        uint4* d = (uint4*)&Ws[r][p * 64];
        #pragma unroll
        for (int i = 0; i < 8; i++) d[i] = s[i];
    }
    int row0 = blockIdx.x * 64;
    {
        int r = t >> 2, p = t & 3;
        int g = row0 + r;
        const uint4* s = (const uint4*)(A + (size_t)g * 128 + p * 32);
        uint4* d = (uint4*)&As[r][p * 32];
        #pragma unroll
        for (int i = 0; i < 4; i++) {
            uint4 v = make_uint4(0, 0, 0, 0);
            if (g < n) v = s[i];
            d[i] = v;
        }
    }
    __syncthreads();

    int w = t >> 6, lane = t & 63;
    int lm = lane & 15, lq = lane >> 4;
    f32x4 acc[8];
    #pragma unroll
    for (int c = 0; c < 8; c++) acc[c] = (f32x4){0.f, 0.f, 0.f, 0.f};
    #pragma unroll
    for (int kk = 0; kk < 4; kk++) {
        bf16x8 af = *(const bf16x8*)&As[w * 16 + lm][kk * 32 + lq * 8];
        #pragma unroll
        for (int c = 0; c < 8; c++) {
            bf16x8 bf = *(const bf16x8*)&Ws[c * 16 + lm][kk * 32 + lq * 8];
            acc[c] = __builtin_amdgcn_mfma_f32_16x16x32_bf16(af, bf, acc[c], 0, 0, 0);
        }
    }
    #pragma unroll
    for (int c = 0; c < 8; c++) {
        #pragma unroll
        for (int r = 0; r < 4; r++) {
            int row = row0 + w * 16 + lq * 4 + r;
            int col = c * 16 + lm;
            if (row < n) {
                float v = acc[c][r] + bias[col];
                v = v > 0.f ? v : 0.f;
                C[(size_t)row * 128 + col] = f2bf(v);
            }
        }
    }
}

extern "C" void kernel_launch(void* const* d_in, const int* in_sizes, int n_in,
                              void* d_out, int out_size, void* d_ws, size_t ws_size,
                              hipStream_t stream) {
    const float* x   = (const float*)d_in[0];
    const int*   ei  = (const int*)d_in[1];
    const float* W1a = (const float*)d_in[2];
    const float* b1a = (const float*)d_in[3];
    const float* W1b = (const float*)d_in[4];
    const float* b1b = (const float*)d_in[5];
    const float* W2a = (const float*)d_in[6];
    const float* b2a = (const float*)d_in[7];
    const float* W2b = (const float*)d_in[8];
    const float* b2b = (const float*)d_in[9];
    const float* Wfc = (const float*)d_in[10];
    const float* bfc = (const float*)d_in[11];

    const int* esrc = ei;
    const int* edst = ei + N_EDGES;

    char* w = (char*)d_ws;
    size_t off = 0;
    auto alloc = [&](size_t bytes) -> char* {
        char* p = w + off;
        off = (off + bytes + 255) & ~(size_t)255;
        return p;
    };
    int*   offs       = (int*)alloc((N_NODES + 1) * 4);
    int*   startTab   = (int*)alloc((size_t)B_A * NBUK * 4);
    int*   cntTab     = (int*)alloc((size_t)B_A * NBUK * 4);
    int*   bucketBase = (int*)alloc(NBUK * 4);
    int*   csr        = (int*)alloc((size_t)N_EDGES * 4);
    u16*   wt1a       = (u16*)alloc(128 * 128 * 2);
    u16*   wt1b       = (u16*)alloc(128 * 128 * 2);
    u16*   wt2a       = (u16*)alloc(128 * 128 * 2);
    float* Wc         = (float*)alloc(256 * 4);
    float* bc         = (float*)alloc(2 * 4);
    u16*   bufA       = (u16*)alloc((size_t)N_NODES * 128 * 2);
    u16*   bufB       = (u16*)alloc((size_t)N_NODES * 128 * 2);
    // binned edge staging aliases bufA: consumed by binB before fused1 writes bufA
    u32*   binned     = (u32*)bufA;

    prep_kernel<<<193, 256, 0, stream>>>(W1a, W1b, W2a, W2b, Wfc, b2b, bfc,
                                         wt1a, wt1b, wt2a, Wc, bc);
    // binA also converts x (fp32) -> bufB (packed bf16)
    binA_kernel<<<B_A, 256, 0, stream>>>(esrc, edst, binned, startTab, cntTab,
                                         x, (u32*)bufB);
    bscan_kernel<<<1, 256, 0, stream>>>(cntTab, bucketBase, offs);
    binB_kernel<<<NBUK, 256, 0, stream>>>(binned, startTab, cntTab, bucketBase, offs, csr);

    const int TILES = (N_NODES + 63) / 64;

    // conv1: fused agg+gemm(W1a)+relu -> bufA ; gemm(W1b)+outer relu -> bufB (=h1)
    fused_agg_gemm<0><<<TILES, 256, 0, stream>>>((const u32*)bufB, wt1a, b1a,
                                                 offs, csr, bufA,
                                                 nullptr, nullptr, nullptr, N_NODES);
    gemm_relu_kernel<<<TILES, 256, 0, stream>>>(bufA, wt1b, b1b, bufB, N_NODES);
    // conv2 + fc: fused agg+gemm(W2a)+relu, epilogue @ Wc + bc -> d_out (fp32)
    fused_agg_gemm<1><<<TILES, 256, 0, stream>>>((const u32*)bufB, wt2a, b2a,
                                                 offs, csr, nullptr,
                                                 Wc, bc, (float2*)d_out, N_NODES);
}

// Round 6
// 266.605 us; speedup vs baseline: 1.0909x; 1.0909x over previous
//
#include <hip/hip_runtime.h>

#define N_NODES 50000
#define N_EDGES 800000
#define CH      128
#define NBUK    196          // buckets of 256 nodes: dst>>8, max 49999>>8 = 195
#define B_A     128          // phase-A blocks
#define EPB     6250         // edges per phase-A block (128*6250 = 800000)
#define CAP     5120         // LDS capacity per bucket in phase B (mean 4096)

typedef unsigned short u16;
typedef unsigned int   u32;
typedef __bf16 bf16x8 __attribute__((ext_vector_type(8)));
typedef float  f32x4  __attribute__((ext_vector_type(4)));

__device__ __forceinline__ float bf_lo(u32 v){ return __uint_as_float(v << 16); }
__device__ __forceinline__ float bf_hi(u32 v){ return __uint_as_float(v & 0xffff0000u); }
__device__ __forceinline__ u32 bf_pack(float a, float b){
    u32 ua = __float_as_uint(a), ub = __float_as_uint(b);
    ua += 0x7fffu + ((ua >> 16) & 1u);
    ub += 0x7fffu + ((ub >> 16) & 1u);
    return (ua >> 16) | (ub & 0xffff0000u);
}
__device__ __forceinline__ u16 f2bf(float a){
    u32 ua = __float_as_uint(a);
    ua += 0x7fffu + ((ua >> 16) & 1u);
    return (u16)(ua >> 16);
}
__device__ __forceinline__ void addu4(uint4 v, float* a){
    a[0] += bf_lo(v.x); a[1] += bf_hi(v.x);
    a[2] += bf_lo(v.y); a[3] += bf_hi(v.y);
    a[4] += bf_lo(v.z); a[5] += bf_hi(v.z);
    a[6] += bf_lo(v.w); a[7] += bf_hi(v.w);
}

// inclusive block-scan of one int per thread (256 threads, 4 waves)
__device__ __forceinline__ int blockScan256(int v, int* ws, int t) {
    int lane = t & 63, w = t >> 6;
    #pragma unroll
    for (int off = 1; off < 64; off <<= 1) {
        int u = __shfl_up(v, off);
        if (lane >= off) v += u;
    }
    if (lane == 63) ws[w] = v;
    __syncthreads();
    int add = 0;
    for (int k = 0; k < w; k++) add += ws[k];
    return v + add;
}

// ---- prep: transpose W1a/W1b/W2a (fp32 [in][out]) -> bf16 [out][in];
//      fold Wc = W2b@Wfc (fp32), bc = b2b@Wfc + bfc (fp32)
__global__ void prep_kernel(const float* __restrict__ W1a, const float* __restrict__ W1b,
                            const float* __restrict__ W2a, const float* __restrict__ W2b,
                            const float* __restrict__ Wfc, const float* __restrict__ b2b,
                            const float* __restrict__ bfc,
                            u16* __restrict__ wt1a, u16* __restrict__ wt1b,
                            u16* __restrict__ wt2a,
                            float* __restrict__ Wc, float* __restrict__ bc) {
    int b = blockIdx.x, t = threadIdx.x;
    if (b < 192) {
        int g  = b * 256 + t;
        int mi = g >> 14;
        int p  = g & 16383;
        int k  = p >> 7, m = p & 127;
        const float* src = (mi == 0) ? W1a : (mi == 1) ? W1b : W2a;
        u16* dst         = (mi == 0) ? wt1a : (mi == 1) ? wt1b : wt2a;
        dst[m * 128 + k] = f2bf(src[k * 128 + m]);
    } else {
        int j = t >> 1, o = t & 1;
        float s = 0.f;
        for (int k = 0; k < 128; k++)
            s += W2b[j * 128 + k] * Wfc[k * 2 + o];
        Wc[j * 2 + o] = s;
        if (t < 2) {
            float s2 = 0.f;
            for (int k = 0; k < 128; k++)
                s2 += b2b[k] * Wfc[k * 2 + t];
            bc[t] = s2 + bfc[t];
        }
    }
}

// ---- CSR phase A: per-block bucket sort (dst>>8) staged in LDS, linear flush.
//      + grid-stride fp32->bf16 conversion of x appended (independent work).
__launch_bounds__(256)
__global__ void binA_kernel(const int* __restrict__ esrc, const int* __restrict__ edst,
                            u32* __restrict__ binned, int* __restrict__ startTab,
                            int* __restrict__ cntTab,
                            const float* __restrict__ xsrc, u32* __restrict__ xb) {
    __shared__ int hist[NBUK];
    __shared__ int cur[NBUK];
    __shared__ u32 ebuf[EPB];
    __shared__ int ws[4];
    int t = threadIdx.x, blk = blockIdx.x;
    int base = blk * EPB;
    for (int i = t; i < NBUK; i += 256) hist[i] = 0;
    __syncthreads();
    for (int i = t; i < EPB; i += 256)
        atomicAdd(&hist[edst[base + i] >> 8], 1);
    __syncthreads();
    int v = (t < NBUK) ? hist[t] : 0;
    int incl = blockScan256(v, ws, t);
    int excl = incl - v;
    if (t < NBUK) {
        startTab[blk * NBUK + t] = excl;
        cntTab[blk * NBUK + t]   = v;
        cur[t] = excl;
    }
    __syncthreads();
    for (int i = t; i < EPB; i += 256) {
        int d = edst[base + i], s = esrc[base + i];
        int p = atomicAdd(&cur[d >> 8], 1);
        ebuf[p] = (u32)s | ((u32)(d & 255) << 16);   // src(16b) | dst_local(8b)
    }
    __syncthreads();
    for (int i = t; i < EPB; i += 256)               // linear flush: full lines
        binned[base + i] = ebuf[i];
    // fp32 x -> packed bf16 (grid-stride, independent of binning)
    const int total = N_NODES * 64;
    for (int i = blk * 256 + t; i < total; i += B_A * 256) {
        float2 f = ((const float2*)xsrc)[i];
        xb[i] = bf_pack(f.x, f.y);
    }
}

// bucket totals + exclusive scan (tiny)
__global__ void bscan_kernel(const int* __restrict__ cntTab, int* __restrict__ bucketBase,
                             int* __restrict__ offs) {
    __shared__ int ws[4];
    int t = threadIdx.x;
    int s = 0;
    if (t < NBUK) {
        #pragma unroll 8
        for (int blk = 0; blk < B_A; blk++) s += cntTab[blk * NBUK + t];
    }
    int incl = blockScan256(s, ws, t);
    if (t < NBUK) bucketBase[t] = incl - s;
    if (t == 0) offs[N_NODES] = N_EDGES;
}

// ---- CSR phase B: one block per bucket; gather runs, local sort in LDS,
//      linear flush to csr; write offs.
__launch_bounds__(256)
__global__ void binB_kernel(const u32* __restrict__ binned, const int* __restrict__ startTab,
                            const int* __restrict__ cntTab, const int* __restrict__ bucketBase,
                            int* __restrict__ offs, int* __restrict__ csr) {
    __shared__ u32 ebuf[CAP];
    __shared__ int cbuf[CAP];
    __shared__ int runoff[B_A + 1];
    __shared__ int runstart[B_A];
    __shared__ int hist[256];
    __shared__ int cursor[256];
    __shared__ int ws[4];
    int b = blockIdx.x, t = threadIdx.x;
    int c = (t < B_A) ? cntTab[t * NBUK + b] : 0;
    int incl = blockScan256(c, ws, t);
    if (t < B_A) {
        runoff[t]   = incl - c;
        runstart[t] = t * EPB + startTab[t * NBUK + b];
    }
    if (t == B_A - 1) runoff[B_A] = incl;
    hist[t] = 0;
    __syncthreads();
    int tot = runoff[B_A];
    if (tot > CAP) tot = CAP;
    for (int i = t; i < tot; i += 256) { // flat gather: binary search run
        int lo = 0, hi = B_A;
        while (hi - lo > 1) {
            int mid = (lo + hi) >> 1;
            if (runoff[mid] <= i) lo = mid; else hi = mid;
        }
        ebuf[i] = binned[runstart[lo] + (i - runoff[lo])];
    }
    __syncthreads();
    for (int i = t; i < tot; i += 256)
        atomicAdd(&hist[ebuf[i] >> 16], 1);
    __syncthreads();
    int hv = hist[t];
    int hincl = blockScan256(hv, ws, t);
    int hexcl = hincl - hv;
    cursor[t] = hexcl;
    int node = (b << 8) + t;
    if (node < N_NODES) offs[node] = bucketBase[b] + hexcl;
    __syncthreads();
    for (int i = t; i < tot; i += 256) {
        u32 e = ebuf[i];
        int p = atomicAdd(&cursor[e >> 16], 1);
        cbuf[p] = (int)(e & 0xFFFFu);
    }
    __syncthreads();
    int gb = bucketBase[b];
    for (int i = t; i < tot; i += 256)
        csr[gb + i] = cbuf[i];
}

// ---- fused agg + GEMM ------------------------------------------------------
// A-tile (64 rows) produced in-kernel (gather + fp32 acc -> bf16 -> LDS).
// W is NOT staged in LDS: B-fragments are loaded straight from global (32 KB,
// L1/L2-resident across blocks). LDS = As only (17.4 KB) -> high occupancy
// for the latency-bound gather phase (round-5 regression root cause).
// MODE 0: C = relu(A@W + bias) -> bf16 global.
// MODE 1: out = relu(A@W + bias) @ Wc + bc -> fp32 [n,2]  (FC folded)
template<int MODE>
__launch_bounds__(256, 4)
__global__ void fused_agg_gemm(const u32* __restrict__ xb, const u16* __restrict__ Wt,
                               const float* __restrict__ bias,
                               const int* __restrict__ offs, const int* __restrict__ csr,
                               u16* __restrict__ C,
                               const float* __restrict__ Wc, const float* __restrict__ bc,
                               float2* __restrict__ out, int n) {
    __shared__ u16 As[64][136];
    int t = threadIdx.x;
    int row0 = blockIdx.x * 64;
    int w = t >> 6, lane = t & 63;
    int g4 = lane >> 4, l16 = lane & 15;
    const uint4* xp = (const uint4*)xb;       // row = 16 x uint4 (128 bf16)
    #pragma unroll
    for (int p = 0; p < 4; p++) {             // 4 nodes/wave/pass, 4 passes
        int rl = w * 16 + p * 4 + g4;
        int node = row0 + rl;
        float a[8] = {0.f,0.f,0.f,0.f,0.f,0.f,0.f,0.f};
        if (node < n) {
            addu4(xp[(size_t)node * 16 + l16], a);   // self term
            int j = offs[node], jend = offs[node + 1];
            for (; j + 4 <= jend; j += 4) {
                int s0 = csr[j], s1 = csr[j + 1], s2 = csr[j + 2], s3 = csr[j + 3];
                uint4 w0 = xp[(size_t)s0 * 16 + l16];
                uint4 w1 = xp[(size_t)s1 * 16 + l16];
                uint4 w2 = xp[(size_t)s2 * 16 + l16];
                uint4 w3 = xp[(size_t)s3 * 16 + l16];
                addu4(w0, a); addu4(w1, a); addu4(w2, a); addu4(w3, a);
            }
            for (; j < jend; j++)
                addu4(xp[(size_t)csr[j] * 16 + l16], a);
        }
        uint4 pk = make_uint4(bf_pack(a[0], a[1]), bf_pack(a[2], a[3]),
                              bf_pack(a[4], a[5]), bf_pack(a[6], a[7]));
        *(uint4*)&As[rl][l16 * 8] = pk;
    }
    __syncthreads();

    int lm = lane & 15, lq = lane >> 4;
    f32x4 acc[8];
    #pragma unroll
    for (int c = 0; c < 8; c++) acc[c] = (f32x4){0.f, 0.f, 0.f, 0.f};
    #pragma unroll
    for (int kk = 0; kk < 4; kk++) {
        bf16x8 af = *(const bf16x8*)&As[w * 16 + lm][kk * 32 + lq * 8];
        #pragma unroll
        for (int c = 0; c < 8; c++) {
            bf16x8 bf = *(const bf16x8*)(Wt + (size_t)(c * 16 + lm) * 128 + kk * 32 + lq * 8);
            acc[c] = __builtin_amdgcn_mfma_f32_16x16x32_bf16(af, bf, acc[c], 0, 0, 0);
        }
    }
    if (MODE == 0) {
        #pragma unroll
        for (int c = 0; c < 8; c++) {
            #pragma unroll
            for (int r = 0; r < 4; r++) {
                int row = row0 + w * 16 + lq * 4 + r;
                int col = c * 16 + lm;
                if (row < n) {
                    float v = acc[c][r] + bias[col];
                    v = v > 0.f ? v : 0.f;
                    C[(size_t)row * 128 + col] = f2bf(v);
                }
            }
        }
    } else {
        float p0[4] = {0,0,0,0}, p1[4] = {0,0,0,0};
        #pragma unroll
        for (int c = 0; c < 8; c++) {
            int col = c * 16 + lm;
            float bcol = bias[col];
            float2 wc = ((const float2*)Wc)[col];
            #pragma unroll
            for (int r = 0; r < 4; r++) {
                float v = acc[c][r] + bcol;
                v = v > 0.f ? v : 0.f;
                p0[r] += v * wc.x;
                p1[r] += v * wc.y;
            }
        }
        #pragma unroll
        for (int off = 1; off < 16; off <<= 1) {
            #pragma unroll
            for (int r = 0; r < 4; r++) {
                p0[r] += __shfl_xor(p0[r], off);
                p1[r] += __shfl_xor(p1[r], off);
            }
        }
        if (lm == 0) {
            float b0 = bc[0], b1 = bc[1];
            #pragma unroll
            for (int r = 0; r < 4; r++) {
                int row = row0 + w * 16 + lq * 4 + r;
                if (row < n) out[row] = make_float2(p0[r] + b0, p1[r] + b1);
            }
        }
    }
}

// ---- plain GEMM (conv1 second linear + outer relu) -------------------------
__launch_bounds__(256)
__global__ void gemm_relu_kernel(const u16* __restrict__ A, const u16* __restrict__ Wt,
                                 const float* __restrict__ bias, u16* __restrict__ C,
                                 int n) {
    __shared__ u16 Ws[128][136];
    __shared__ u16 As[64][136];
    int t = threadIdx.x;
    {
        int r = t >> 1, p = t & 1;
        const uint4* s = (const uint4*)(Wt + r * 128 + p * 64);
        uint4* d = (uint4*)&Ws[r][p * 64];
        #pragma unroll
        for (int i = 0; i < 8; i++) d[i] = s[i];
    }
    int row0 = blockIdx.x * 64;
    {
        int r = t >> 2, p = t & 3;
        int g = row0 + r;
        const uint4* s = (const uint4*)(A + (size_t)g * 128 + p * 32);
        uint4* d = (uint4*)&As[r][p * 32];
        #pragma unroll
        for (int i = 0; i < 4; i++) {
            uint4 v = make_uint4(0, 0, 0, 0);
            if (g < n) v = s[i];
            d[i] = v;
        }
    }
    __syncthreads();

    int w = t >> 6, lane = t & 63;
    int lm = lane & 15, lq = lane >> 4;
    f32x4 acc[8];
    #pragma unroll
    for (int c = 0; c < 8; c++) acc[c] = (f32x4){0.f, 0.f, 0.f, 0.f};
    #pragma unroll
    for (int kk = 0; kk < 4; kk++) {
        bf16x8 af = *(const bf16x8*)&As[w * 16 + lm][kk * 32 + lq * 8];
        #pragma unroll
        for (int c = 0; c < 8; c++) {
            bf16x8 bf = *(const bf16x8*)&Ws[c * 16 + lm][kk * 32 + lq * 8];
            acc[c] = __builtin_amdgcn_mfma_f32_16x16x32_bf16(af, bf, acc[c], 0, 0, 0);
        }
    }
    #pragma unroll
    for (int c = 0; c < 8; c++) {
        #pragma unroll
        for (int r = 0; r < 4; r++) {
            int row = row0 + w * 16 + lq * 4 + r;
            int col = c * 16 + lm;
            if (row < n) {
                float v = acc[c][r] + bias[col];
                v = v > 0.f ? v : 0.f;
                C[(size_t)row * 128 + col] = f2bf(v);
            }
        }
    }
}

extern "C" void kernel_launch(void* const* d_in, const int* in_sizes, int n_in,
                              void* d_out, int out_size, void* d_ws, size_t ws_size,
                              hipStream_t stream) {
    const float* x   = (const float*)d_in[0];
    const int*   ei  = (const int*)d_in[1];
    const float* W1a = (const float*)d_in[2];
    const float* b1a = (const float*)d_in[3];
    const float* W1b = (const float*)d_in[4];
    const float* b1b = (const float*)d_in[5];
    const float* W2a = (const float*)d_in[6];
    const float* b2a = (const float*)d_in[7];
    const float* W2b = (const float*)d_in[8];
    const float* b2b = (const float*)d_in[9];
    const float* Wfc = (const float*)d_in[10];
    const float* bfc = (const float*)d_in[11];

    const int* esrc = ei;
    const int* edst = ei + N_EDGES;

    char* w = (char*)d_ws;
    size_t off = 0;
    auto alloc = [&](size_t bytes) -> char* {
        char* p = w + off;
        off = (off + bytes + 255) & ~(size_t)255;
        return p;
    };
    int*   offs       = (int*)alloc((N_NODES + 1) * 4);
    int*   startTab   = (int*)alloc((size_t)B_A * NBUK * 4);
    int*   cntTab     = (int*)alloc((size_t)B_A * NBUK * 4);
    int*   bucketBase = (int*)alloc(NBUK * 4);
    int*   csr        = (int*)alloc((size_t)N_EDGES * 4);
    u16*   wt1a       = (u16*)alloc(128 * 128 * 2);
    u16*   wt1b       = (u16*)alloc(128 * 128 * 2);
    u16*   wt2a       = (u16*)alloc(128 * 128 * 2);
    float* Wc         = (float*)alloc(256 * 4);
    float* bc         = (float*)alloc(2 * 4);
    u16*   bufA       = (u16*)alloc((size_t)N_NODES * 128 * 2);
    u16*   bufB       = (u16*)alloc((size_t)N_NODES * 128 * 2);
    // binned edge staging aliases bufA: consumed by binB before fused1 writes bufA
    u32*   binned     = (u32*)bufA;

    prep_kernel<<<193, 256, 0, stream>>>(W1a, W1b, W2a, W2b, Wfc, b2b, bfc,
                                         wt1a, wt1b, wt2a, Wc, bc);
    // binA also converts x (fp32) -> bufB (packed bf16)
    binA_kernel<<<B_A, 256, 0, stream>>>(esrc, edst, binned, startTab, cntTab,
                                         x, (u32*)bufB);
    bscan_kernel<<<1, 256, 0, stream>>>(cntTab, bucketBase, offs);
    binB_kernel<<<NBUK, 256, 0, stream>>>(binned, startTab, cntTab, bucketBase, offs, csr);

    const int TILES = (N_NODES + 63) / 64;

    // conv1: fused agg+gemm(W1a)+relu -> bufA ; gemm(W1b)+outer relu -> bufB (=h1)
    fused_agg_gemm<0><<<TILES, 256, 0, stream>>>((const u32*)bufB, wt1a, b1a,
                                                 offs, csr, bufA,
                                                 nullptr, nullptr, nullptr, N_NODES);
    gemm_relu_kernel<<<TILES, 256, 0, stream>>>(bufA, wt1b, b1b, bufB, N_NODES);
    // conv2 + fc: fused agg+gemm(W2a)+relu, epilogue @ Wc + bc -> d_out (fp32)
    fused_agg_gemm<1><<<TILES, 256, 0, stream>>>((const u32*)bufB, wt2a, b2a,
                                                 offs, csr, nullptr,
                                                 Wc, bc, (float2*)d_out, N_NODES);
}